// Round 1
// 1730.999 us; speedup vs baseline: 1.2452x; 1.2452x over previous
//
#include <hip/hip_runtime.h>
#include <cmath>

#define HIDDEN 256
#define NUM_RADIAL 6
#define OUT_EMB 192
#define NUM_LAYERS 3

#define TM 32     // nodes per node_mlp block
#define NPG 8     // nodes per wave (node-group)
#define JT 3      // output columns per thread: j, j+64, j+128

// ---------- edge path: counting sort by node, then gather ----------

__global__ __launch_bounds__(256) void hist_kernel(const int* __restrict__ idx,
                                                   int* __restrict__ counts, int E) {
    const int e = blockIdx.x * 256 + threadIdx.x;
    if (e < E) atomicAdd(&counts[idx[e]], 1);
}

__global__ __launch_bounds__(1024) void scan_kernel(const int* __restrict__ counts,
                                                    int* __restrict__ start,
                                                    int* __restrict__ cursor,
                                                    int N, int E) {
    __shared__ int pref[1024];
    const int t = threadIdx.x;
    const int chunk = (N + 1023) >> 10;
    const int lo = min(t * chunk, N), hi = min(lo + chunk, N);
    int s = 0;
    for (int i = lo; i < hi; i++) s += counts[i];
    pref[t] = s;
    __syncthreads();
    if (t == 0) {
        int run = 0;
        for (int i = 0; i < 1024; i++) { const int v = pref[i]; pref[i] = run; run += v; }
    }
    __syncthreads();
    int run = pref[t];
    for (int i = lo; i < hi; i++) {
        start[i] = run; cursor[i] = run; run += counts[i];
    }
    if (t == 0) start[N] = E;
}

__global__ __launch_bounds__(256) void perm_kernel(const int* __restrict__ idx,
                                                   int* __restrict__ cursor,
                                                   int* __restrict__ perm, int E) {
    const int e = blockIdx.x * 256 + threadIdx.x;
    if (e < E) {
        const int pos = atomicAdd(&cursor[idx[e]], 1);
        perm[pos] = e;
    }
}

// gather v3: 4 nodes per block, 64 lanes x float4 channels.
// One wave instruction fetches a full 1KB x-row; edge loop unrolled x2 so two
// independent HBM row-fetches are in flight per wave.
__device__ __forceinline__ float4 edge_term(const float rv0, const float rv1,
                                            const float rv2, const float rv3,
                                            const float rv4, const float rv5,
                                            const float4* wr, const float4 xv) {
    float4 g;
    g.x = rv0*wr[0].x + rv1*wr[1].x + rv2*wr[2].x + rv3*wr[3].x + rv4*wr[4].x + rv5*wr[5].x;
    g.y = rv0*wr[0].y + rv1*wr[1].y + rv2*wr[2].y + rv3*wr[3].y + rv4*wr[4].y + rv5*wr[5].y;
    g.z = rv0*wr[0].z + rv1*wr[1].z + rv2*wr[2].z + rv3*wr[3].z + rv4*wr[4].z + rv5*wr[5].z;
    g.w = rv0*wr[0].w + rv1*wr[1].w + rv2*wr[2].w + rv3*wr[3].w + rv4*wr[4].w + rv5*wr[5].w;
    return make_float4(g.x*xv.x, g.y*xv.y, g.z*xv.z, g.w*xv.w);
}

__global__ __launch_bounds__(256) void gather_kernel(
    const float* __restrict__ x, const float* __restrict__ rbf,
    const int* __restrict__ perm, const int* __restrict__ start,
    const float* __restrict__ W_rbf, float* __restrict__ xn, int N)
{
    const int lane = threadIdx.x & 63;
    const int slot = threadIdx.x >> 6;
    const int n = blockIdx.x * 4 + slot;
    if (n >= N) return;
    const int c0 = lane << 2;

    float4 wr[NUM_RADIAL];
    #pragma unroll
    for (int r = 0; r < NUM_RADIAL; r++)
        wr[r] = *(const float4*)&W_rbf[r * HIDDEN + c0];

    const int p0 = start[n], p1 = start[n + 1];
    float4 acc = make_float4(0.f, 0.f, 0.f, 0.f);

    int p = p0;
    for (; p + 2 <= p1; p += 2) {
        const int e0 = perm[p];
        const int e1 = perm[p + 1];
        const float2* rb0 = (const float2*)(rbf + (size_t)e0 * NUM_RADIAL);
        const float2* rb1 = (const float2*)(rbf + (size_t)e1 * NUM_RADIAL);
        const float2 a0 = rb0[0], a1 = rb0[1], a2 = rb0[2];
        const float2 b0 = rb1[0], b1 = rb1[1], b2 = rb1[2];
        const float4 xv0 = *(const float4*)&x[(size_t)e0 * HIDDEN + c0];
        const float4 xv1 = *(const float4*)&x[(size_t)e1 * HIDDEN + c0];
        const float4 t0 = edge_term(a0.x, a0.y, a1.x, a1.y, a2.x, a2.y, wr, xv0);
        const float4 t1 = edge_term(b0.x, b0.y, b1.x, b1.y, b2.x, b2.y, wr, xv1);
        acc.x += t0.x + t1.x; acc.y += t0.y + t1.y;
        acc.z += t0.z + t1.z; acc.w += t0.w + t1.w;
    }
    if (p < p1) {
        const int e0 = perm[p];
        const float2* rb0 = (const float2*)(rbf + (size_t)e0 * NUM_RADIAL);
        const float2 a0 = rb0[0], a1 = rb0[1], a2 = rb0[2];
        const float4 xv0 = *(const float4*)&x[(size_t)e0 * HIDDEN + c0];
        const float4 t0 = edge_term(a0.x, a0.y, a1.x, a1.y, a2.x, a2.y, wr, xv0);
        acc.x += t0.x; acc.y += t0.y; acc.z += t0.z; acc.w += t0.w;
    }
    *(float4*)&xn[(size_t)n * HIDDEN + c0] = acc;
}

// ---------- node MLP v3: 3 cols/thread x 8 nodes, xn via wave-broadcast global ----------
// Each 16B operand read now feeds 12 FMAs (was 4) -> FMA pipe becomes critical.
// LDS = hl only (24KB); 256 thr, <=128 VGPR -> 4 blocks/CU = 16 waves/CU.

__global__ __launch_bounds__(256, 4) void node_mlp(
    const float* __restrict__ xn,
    const float* __restrict__ W_up, const float* __restrict__ b_up,
    const float* __restrict__ W_lins, const float* __restrict__ b_lins,
    const float* __restrict__ W_out,
    float* __restrict__ out, int N)
{
    __shared__ float hl[TM * OUT_EMB];      // 24 KB
    const int t = threadIdx.x;
    const int j = t & 63;
    const int g = t >> 6;                   // wave id = node group
    const int nbase = blockIdx.x * TM;
    const int n0 = g * NPG;

    float acc[NPG][JT];

    // wave-uniform row pointers (clamped for the tail block; OOB rows produce
    // garbage that is never stored)
    const float* xrow[NPG];
    #pragma unroll
    for (int n = 0; n < NPG; n++) {
        int nn = nbase + n0 + n;
        if (nn > N - 1) nn = N - 1;
        xrow[n] = xn + (size_t)nn * HIDDEN;
    }

    // ---- layer 1: h = xn @ W_up + b_up   (K = 256, xn read via broadcast L1) ----
    {
        float bj[JT];
        #pragma unroll
        for (int m = 0; m < JT; m++) bj[m] = b_up[j + 64 * m];
        #pragma unroll
        for (int n = 0; n < NPG; n++)
            #pragma unroll
            for (int m = 0; m < JT; m++) acc[n][m] = bj[m];

        for (int c0 = 0; c0 < HIDDEN; c0 += 8) {
            float w[8][JT];
            #pragma unroll
            for (int k = 0; k < 8; k++)
                #pragma unroll
                for (int m = 0; m < JT; m++)
                    w[k][m] = W_up[(c0 + k) * OUT_EMB + j + 64 * m];
            #pragma unroll
            for (int n = 0; n < NPG; n++) {
                #pragma unroll
                for (int k4 = 0; k4 < 8; k4 += 4) {
                    const float4 xv = *(const float4*)(xrow[n] + c0 + k4);
                    #pragma unroll
                    for (int m = 0; m < JT; m++)
                        acc[n][m] += xv.x * w[k4 + 0][m] + xv.y * w[k4 + 1][m]
                                   + xv.z * w[k4 + 2][m] + xv.w * w[k4 + 3][m];
                }
            }
        }
        #pragma unroll
        for (int n = 0; n < NPG; n++)
            #pragma unroll
            for (int m = 0; m < JT; m++)
                hl[(n0 + n) * OUT_EMB + j + 64 * m] = acc[n][m];
        __syncthreads();
    }

    // ---- layers 2..4: h = silu(h @ W_lins[l] + b_lins[l])   (K = 192) ----
    for (int l = 0; l < NUM_LAYERS; l++) {
        const float* __restrict__ W = W_lins + (size_t)l * OUT_EMB * OUT_EMB;
        float bj[JT];
        #pragma unroll
        for (int m = 0; m < JT; m++) bj[m] = b_lins[l * OUT_EMB + j + 64 * m];
        #pragma unroll
        for (int n = 0; n < NPG; n++)
            #pragma unroll
            for (int m = 0; m < JT; m++) acc[n][m] = bj[m];

        for (int c0 = 0; c0 < OUT_EMB; c0 += 8) {
            float w[8][JT];
            #pragma unroll
            for (int k = 0; k < 8; k++)
                #pragma unroll
                for (int m = 0; m < JT; m++)
                    w[k][m] = W[(c0 + k) * OUT_EMB + j + 64 * m];
            #pragma unroll
            for (int n = 0; n < NPG; n++) {
                #pragma unroll
                for (int k4 = 0; k4 < 8; k4 += 4) {
                    const float4 hv = *(const float4*)&hl[(n0 + n) * OUT_EMB + c0 + k4];
                    #pragma unroll
                    for (int m = 0; m < JT; m++)
                        acc[n][m] += hv.x * w[k4 + 0][m] + hv.y * w[k4 + 1][m]
                                   + hv.z * w[k4 + 2][m] + hv.w * w[k4 + 3][m];
                }
            }
        }
        __syncthreads();   // all reads of hl complete before overwrite
        #pragma unroll
        for (int n = 0; n < NPG; n++)
            #pragma unroll
            for (int m = 0; m < JT; m++) {
                const float a = acc[n][m];
                hl[(n0 + n) * OUT_EMB + j + 64 * m] = a / (1.f + __expf(-a));  // silu
            }
        __syncthreads();
    }

    // ---- out = h @ W_out  (OUT = 1): 8 lanes per node, shfl-reduce ----
    {
        const int n = t >> 3;      // 0..31
        const int sub = t & 7;
        float s = 0.f;
        #pragma unroll
        for (int q = 0; q < 24; q += 4) {
            const float4 hv = *(const float4*)&hl[n * OUT_EMB + sub * 24 + q];
            const float4 wv = *(const float4*)&W_out[sub * 24 + q];
            s += hv.x * wv.x + hv.y * wv.y + hv.z * wv.z + hv.w * wv.w;
        }
        s += __shfl_down(s, 4, 8);
        s += __shfl_down(s, 2, 8);
        s += __shfl_down(s, 1, 8);
        if (sub == 0 && nbase + n < N) out[nbase + n] = s;
    }
}

extern "C" void kernel_launch(void* const* d_in, const int* in_sizes, int n_in,
                              void* d_out, int out_size, void* d_ws, size_t ws_size,
                              hipStream_t stream) {
    const float* x      = (const float*)d_in[0];
    const float* rbf    = (const float*)d_in[1];
    const int*   idx    = (const int*)d_in[2];
    const float* W_rbf  = (const float*)d_in[4];
    const float* W_up   = (const float*)d_in[5];
    const float* b_up   = (const float*)d_in[6];
    const float* W_lins = (const float*)d_in[7];
    const float* b_lins = (const float*)d_in[8];
    const float* W_out  = (const float*)d_in[9];
    float* out = (float*)d_out;

    const int E = in_sizes[2];
    const int N = out_size;

    // workspace layout
    char* ws = (char*)d_ws;
    float* xn     = (float*)ws;                    ws += (size_t)N * HIDDEN * sizeof(float);
    int*   counts = (int*)ws;                      ws += (size_t)N * sizeof(int);
    int*   start  = (int*)ws;                      ws += (size_t)(N + 1) * sizeof(int);
    int*   cursor = (int*)ws;                      ws += (size_t)N * sizeof(int);
    int*   perm   = (int*)ws;

    hipMemsetAsync(counts, 0, (size_t)N * sizeof(int), stream);
    const int eblocks = (E + 255) / 256;
    hist_kernel<<<eblocks, 256, 0, stream>>>(idx, counts, E);
    scan_kernel<<<1, 1024, 0, stream>>>(counts, start, cursor, N, E);
    perm_kernel<<<eblocks, 256, 0, stream>>>(idx, cursor, perm, E);
    gather_kernel<<<(N + 3) / 4, 256, 0, stream>>>(x, rbf, perm, start, W_rbf, xn, N);

    node_mlp<<<(N + TM - 1) / TM, 256, 0, stream>>>(xn, W_up, b_up, W_lins, b_lins,
                                                    W_out, out, N);
}